// Round 4
// baseline (1854.130 us; speedup 1.0000x reference)
//
#include <hip/hip_runtime.h>
#include <hip/hip_bf16.h>

// C[8192,1000] = sign(X) @ sign(W)^T via i8 MFMA (values in {-1,0,+1}).
// pack_w: W fp32 -> i8, pre-tiled [stage][n(1024)][64B] in d_ws.
// bgemm: 512 WGs = 128 M-tiles(64 rows) x split-K 4 -> 2 blocks/CU.
//   8 waves x N=128. K-chunk = 128 (2 stages) per barrier.
//   B REGISTER PIPELINE: st0's 8 B-frags for chunk c+1 are loaded into VGPRs
//   ~650cyc BEFORE the barrier (issued right after chunk c's st0 MFMAs
//   consume the previous copy), so the barrier's vmcnt(0) drain is free and
//   each chunk opens with B in registers (removes the ~250cyc per-chunk L2
//   cold stall measured as the r3 gap: all pipes <25%, occupancy doubled but
//   only -13%). st1's B loads are issued BEFORE the (HBM, slower) X prefetch
//   so their vmcnt wait doesn't transitively drain X.
//   X staging: register-prefetched, XOR-swizzled double-buffered LDS.
//   bx = mtile*4 + kh -> XCD (bx%8) serves one kh quarter (B ws 3.1MB < L2).
// Split-K partials: PLANE layout part[kh][row][col] i16 (r3's [idx][kh]
//   interleave caused ~4x HBM write amplification across XCDs). |partial| <=
//   3072 fits i16; blocks write disjoint planes, no race.
//   reduce sums 4 planes -> float out. Fallback: zero + atomicAdd.

#define K_DIM   12288
#define N_CLS   1000
#define N_PAD   1024
#define KSPLIT  4
#define K_QUART (K_DIM / KSPLIT)         // 3072
#define STAGE_BYTES (N_PAD * 64)         // 65536
#define N_STAGE_TOT (K_DIM / 64)         // 192
#define CHUNK_STAGES 2
#define CHUNK_K  (CHUNK_STAGES * 64)     // 128
#define CHUNKS   (K_QUART / CHUNK_K)     // 24
#define M_TILE   64
#define B_ROWS   8192
#define PLANE    ((size_t)B_ROWS * N_CLS)                  // 8,192,000 outputs
#define WS_W_BYTES ((size_t)N_STAGE_TOT * STAGE_BYTES)     // 12,582,912
#define WS_P_BYTES (PLANE * 2 * KSPLIT)                    // 65,536,000

typedef int int4v __attribute__((ext_vector_type(4)));
typedef unsigned int uint4v __attribute__((ext_vector_type(4)));
typedef short short4v __attribute__((ext_vector_type(4)));

// sign byte: +1 / -1 / 0 (handles +-0.0 exactly)
__device__ __forceinline__ unsigned sign_byte(unsigned bits) {
    unsigned mag = bits & 0x7fffffffu;
    unsigned nz = mag ? 1u : 0u;
    int sgn = ((int)bits) >> 31;
    int v = (((int)nz) ^ sgn) - sgn;
    return (unsigned)(v & 0xff);
}

__device__ __forceinline__ unsigned pack4(uint4v b) {
    return sign_byte(b.x) | (sign_byte(b.y) << 8) |
           (sign_byte(b.z) << 16) | (sign_byte(b.w) << 24);
}

// ---- W pre-pass: one thread -> 16 consecutive packed bytes of (stage, n).
__global__ void pack_w_kernel(const float* __restrict__ w,
                              unsigned char* __restrict__ ws) {
    const int gid = blockIdx.x * 256 + threadIdx.x;   // 786432 total
    const int stage = gid >> 12;                      // 0..191
    const int n = (gid >> 2) & 1023;
    const int q16 = gid & 3;
    const int k = stage * 64 + q16 * 16;
    uint4v o = {0u, 0u, 0u, 0u};
    if (n < N_CLS) {
        const float* p = w + (size_t)n * K_DIM + k;
        o.x = pack4(*reinterpret_cast<const uint4v*>(p));
        o.y = pack4(*reinterpret_cast<const uint4v*>(p + 4));
        o.z = pack4(*reinterpret_cast<const uint4v*>(p + 8));
        o.w = pack4(*reinterpret_cast<const uint4v*>(p + 12));
    }
    *reinterpret_cast<uint4v*>(ws + (size_t)stage * STAGE_BYTES + n * 64 + q16 * 16) = o;
}

__global__ void zero_kernel(float* __restrict__ out) {
    const int i = blockIdx.x * 256 + threadIdx.x;     // 2,048,000 float4
    float4 z = {0.f, 0.f, 0.f, 0.f};
    *reinterpret_cast<float4*>(out + (size_t)i * 4) = z;
}

// 4 i16 planes -> float out; thread handles 4 outputs (4x 8B reads, float4 write)
__global__ void reduce_kernel(const short* __restrict__ part,
                              float* __restrict__ out) {
    const size_t base = ((size_t)blockIdx.x * 256 + threadIdx.x) * 4;
    short4v p0 = *reinterpret_cast<const short4v*>(part + base);
    short4v p1 = *reinterpret_cast<const short4v*>(part + PLANE + base);
    short4v p2 = *reinterpret_cast<const short4v*>(part + 2 * PLANE + base);
    short4v p3 = *reinterpret_cast<const short4v*>(part + 3 * PLANE + base);
    float4 f;
    f.x = (float)((int)p0.x + (int)p1.x + (int)p2.x + (int)p3.x);
    f.y = (float)((int)p0.y + (int)p1.y + (int)p2.y + (int)p3.y);
    f.z = (float)((int)p0.z + (int)p1.z + (int)p2.z + (int)p3.z);
    f.w = (float)((int)p0.w + (int)p1.w + (int)p2.w + (int)p3.w);
    *reinterpret_cast<float4*>(out + base) = f;
}

// ---- main GEMM
template<int USE_PARTIAL>
__global__ __launch_bounds__(512, 4)
void bgemm_kernel(const float* __restrict__ x,
                  const unsigned char* __restrict__ wq,
                  short* __restrict__ part,
                  float* __restrict__ out) {
    // 2 buffers x 64 rows x 32 dwords (128 i8 per row), XOR-swizzled
    __shared__ unsigned x_lds[2][M_TILE * 32];

    const int tid  = threadIdx.x;
    const int wave = tid >> 6;
    const int lane = tid & 63;
    const int q    = lane >> 4;
    const int l15  = lane & 15;
    const int bx   = blockIdx.x;
    const int mtile = bx >> 2;              // 0..127
    const int kh    = bx & 3;               // 0..3 : K quarter; XCD=bx%8 pins kh
    const int m0    = mtile * M_TILE;
    const int nbase = wave * 128;

    int4v acc[4][8];
#pragma unroll
    for (int i = 0; i < 4; ++i)
#pragma unroll
        for (int j = 0; j < 8; ++j)
            acc[i][j] = (int4v){0, 0, 0, 0};

    // staging: thread t -> row t>>3; i-th uint4 covers logical dword i*8+(t&7)
    const int srow = tid >> 3;
    const int scol = tid & 7;
    const float* xp = x + (size_t)(m0 + srow) * K_DIM + kh * K_QUART + scol * 4;
    const int sw_w = (srow & 3) * 8;

    const unsigned char* wqb = wq + (size_t)(kh * (N_STAGE_TOT / KSPLIT)) * STAGE_BYTES
                               + (nbase + l15) * 64 + q * 16;
    const int rsw = (l15 & 3) * 8;

    // ---- prologue: stage X chunk 0, then pre-issue st0 B-frags of chunk 0
    uint4v xr[4];
#pragma unroll
    for (int i = 0; i < 4; ++i)
        xr[i] = __builtin_nontemporal_load(reinterpret_cast<const uint4v*>(xp + i * 32));
#pragma unroll
    for (int i = 0; i < 4; ++i)
        x_lds[0][srow * 32 + (((i * 8 + scol)) ^ sw_w)] = pack4(xr[i]);

    int4v bpre[8];
#pragma unroll
    for (int nt = 0; nt < 8; ++nt)
        bpre[nt] = *reinterpret_cast<const int4v*>(wqb + nt * 1024);
    __syncthreads();

#pragma unroll 2
    for (int c = 0; c < CHUNKS; ++c) {
        const int cur = c & 1;
        const unsigned char* wpc = wqb + (size_t)(c * CHUNK_STAGES) * STAGE_BYTES;

        // st1 B loads first (L2, consumed this chunk) ...
        int4v b1[8];
#pragma unroll
        for (int nt = 0; nt < 8; ++nt)
            b1[nt] = *reinterpret_cast<const int4v*>(wpc + STAGE_BYTES + nt * 1024);
        // ... then the slower HBM X prefetch (consumed at end of chunk)
        if (c + 1 < CHUNKS) {
            const float* xpc = xp + (size_t)(c + 1) * CHUNK_K;
#pragma unroll
            for (int i = 0; i < 4; ++i)
                xr[i] = __builtin_nontemporal_load(reinterpret_cast<const uint4v*>(xpc + i * 32));
        }

        // ---- stage 0: consume bpre
        {
            int4v a[4];
#pragma unroll
            for (int mt = 0; mt < 4; ++mt)
                a[mt] = *reinterpret_cast<const int4v*>(
                    &x_lds[cur][(mt * 16 + l15) * 32 + ((q * 4) ^ rsw)]);
#pragma unroll
            for (int nt = 0; nt < 8; ++nt)
#pragma unroll
                for (int mt = 0; mt < 4; ++mt)
                    acc[mt][nt] = __builtin_amdgcn_mfma_i32_16x16x64_i8(a[mt], bpre[nt], acc[mt][nt], 0, 0, 0);
        }

        // refill bpre with next chunk's st0 frags (in flight across the barrier)
        if (c + 1 < CHUNKS) {
            const unsigned char* wpn = wqb + (size_t)((c + 1) * CHUNK_STAGES) * STAGE_BYTES;
#pragma unroll
            for (int nt = 0; nt < 8; ++nt)
                bpre[nt] = *reinterpret_cast<const int4v*>(wpn + nt * 1024);
        }

        // ---- stage 1: consume b1
        {
            int4v a[4];
#pragma unroll
            for (int mt = 0; mt < 4; ++mt)
                a[mt] = *reinterpret_cast<const int4v*>(
                    &x_lds[cur][(mt * 16 + l15) * 32 + ((16 + q * 4) ^ rsw)]);
#pragma unroll
            for (int nt = 0; nt < 8; ++nt)
#pragma unroll
                for (int mt = 0; mt < 4; ++mt)
                    acc[mt][nt] = __builtin_amdgcn_mfma_i32_16x16x64_i8(a[mt], b1[nt], acc[mt][nt], 0, 0, 0);
        }

        if (c + 1 < CHUNKS) {
#pragma unroll
            for (int i = 0; i < 4; ++i)
                x_lds[cur ^ 1][srow * 32 + (((i * 8 + scol)) ^ sw_w)] = pack4(xr[i]);
        }
        __syncthreads();
    }

    // epilogue: D col(N) = l15 offset, row(M) = q*4 + reg; plane layout per kh
    short* pplane = part + (size_t)kh * PLANE;
#pragma unroll
    for (int mt = 0; mt < 4; ++mt) {
#pragma unroll
        for (int nt = 0; nt < 8; ++nt) {
            const int col = nbase + nt * 16 + l15;
            if (col < N_CLS) {
#pragma unroll
                for (int r = 0; r < 4; ++r) {
                    const int row = m0 + mt * 16 + q * 4 + r;
                    const size_t idx = (size_t)row * N_CLS + col;
                    if (USE_PARTIAL) {
                        pplane[idx] = (short)acc[mt][nt][r];
                    } else {
                        atomicAdd(&out[idx], (float)acc[mt][nt][r]);
                    }
                }
            }
        }
    }
}

extern "C" void kernel_launch(void* const* d_in, const int* in_sizes, int n_in,
                              void* d_out, int out_size, void* d_ws, size_t ws_size,
                              hipStream_t stream) {
    const float* x = (const float*)d_in[0];     // [8192, 12288]
    const float* w = (const float*)d_in[1];     // [1000, 12288]
    float* out = (float*)d_out;                 // [8192, 1000]
    unsigned char* ws = (unsigned char*)d_ws;

    pack_w_kernel<<<3072, 256, 0, stream>>>(w, ws);

    short* part = reinterpret_cast<short*>(ws + WS_W_BYTES);
    const bool use_part = ws_size >= WS_W_BYTES + WS_P_BYTES;
    if (use_part) {
        bgemm_kernel<1><<<512, 512, 0, stream>>>(x, ws, part, out);
        reduce_kernel<<<(B_ROWS * N_CLS) / (4 * 256), 256, 0, stream>>>(part, out);
    } else {
        zero_kernel<<<(B_ROWS * N_CLS) / (4 * 256), 256, 0, stream>>>(out);
        bgemm_kernel<0><<<512, 512, 0, stream>>>(x, ws, part, out);
    }
}